// Round 1
// baseline (1306.116 us; speedup 1.0000x reference)
//
#include <hip/hip_runtime.h>
#include <hip/hip_bf16.h>

#define HH 192
#define WW 192
#define HWPROD (192*192)
#define EPSBN 1e-5f

// ---------------------------------------------------------------------------
// prep: fold BN (inference) into conv weights/biases; transpose lw -> lwT[k][j]
// ---------------------------------------------------------------------------
__global__ void prep_k(const float* __restrict__ w0, const float* __restrict__ b0,
                       const float* __restrict__ g0, const float* __restrict__ beta0,
                       const float* __restrict__ m0, const float* __restrict__ v0,
                       const float* __restrict__ wnw0, const float* __restrict__ wnb0,
                       const float* __restrict__ wng0, const float* __restrict__ wnbe0,
                       const float* __restrict__ wnm0, const float* __restrict__ wnv0,
                       const float* __restrict__ wnw1, const float* __restrict__ wnb1,
                       const float* __restrict__ wng1, const float* __restrict__ wnbe1,
                       const float* __restrict__ wnm1, const float* __restrict__ wnv1,
                       const float* __restrict__ wnw2, const float* __restrict__ wnb2,
                       const float* __restrict__ wng2, const float* __restrict__ wnbe2,
                       const float* __restrict__ wnm2, const float* __restrict__ wnv2,
                       const float* __restrict__ lw, const float* __restrict__ lb,
                       const float* __restrict__ lg, const float* __restrict__ lbeta,
                       const float* __restrict__ lm, const float* __restrict__ lv,
                       float* __restrict__ lwT, float* __restrict__ lbf,
                       float* __restrict__ w0f, float* __restrict__ b0f,
                       float* __restrict__ wnP)
{
    int idx = blockIdx.x * 256 + threadIdx.x;
    if (idx < 65536) {
        int j = idx & 63, k = idx >> 6;
        float s = lg[j] * rsqrtf(lv[j] + EPSBN);
        lwT[idx] = lw[j * 1024 + k] * s;          // lwT[k][j], fused scale
    } else if (idx < 65600) {
        int j = idx - 65536;
        float s = lg[j] * rsqrtf(lv[j] + EPSBN);
        lbf[j] = (lb[j] - lm[j]) * s + lbeta[j];
    } else if (idx < 66624) {
        int t = idx - 65600;
        int o = t >> 4;
        float s = g0[o] * rsqrtf(v0[o] + EPSBN);
        w0f[t] = w0[t] * s;
    } else if (idx < 66688) {
        int o = idx - 66624;
        float s = g0[o] * rsqrtf(v0[o] + EPSBN);
        b0f[o] = (b0[o] - m0[o]) * s + beta0[o];
    } else if (idx < 66936) {
        int t = idx - 66688;
        // wnP layout: [0,24) w0n  [24,32) b0n  [32,96) w1n  [96,104) b1n
        //             [104,232) w2n  [232,248) b2n   (all BN-fused)
        if (t < 24)       { int o = t / 3;           float s = wng0[o] * rsqrtf(wnv0[o] + EPSBN); wnP[t] = wnw0[t] * s; }
        else if (t < 32)  { int o = t - 24;          float s = wng0[o] * rsqrtf(wnv0[o] + EPSBN); wnP[t] = (wnb0[o] - wnm0[o]) * s + wnbe0[o]; }
        else if (t < 96)  { int t2 = t - 32;  int o = t2 >> 3; float s = wng1[o] * rsqrtf(wnv1[o] + EPSBN); wnP[t] = wnw1[t2] * s; }
        else if (t < 104) { int o = t - 96;          float s = wng1[o] * rsqrtf(wnv1[o] + EPSBN); wnP[t] = (wnb1[o] - wnm1[o]) * s + wnbe1[o]; }
        else if (t < 232) { int t2 = t - 104; int o = t2 >> 3; float s = wng2[o] * rsqrtf(wnv2[o] + EPSBN); wnP[t] = wnw2[t2] * s; }
        else              { int o = t - 232;         float s = wng2[o] * rsqrtf(wnv2[o] + EPSBN); wnP[t] = (wnb2[o] - wnm2[o]) * s + wnbe2[o]; }
    }
}

// ---------------------------------------------------------------------------
// conv0: x[B,16,H,W] -> x1 = relu(bn(conv1x1)) stored pixel-major [B,H,W,64]
// one wave = one pixel (lanes = 64 out channels); inputs are broadcast loads
// ---------------------------------------------------------------------------
__global__ __launch_bounds__(256) void conv0_k(const float* __restrict__ x,
                                               const float* __restrict__ w0f,
                                               const float* __restrict__ b0f,
                                               float* __restrict__ x1L)
{
    __shared__ float wSt[16][64];   // [cin][cout] so lane reads are conflict-free
    __shared__ float bS[64];
    int tid = threadIdx.x;
    for (int t = tid; t < 1024; t += 256) {
        wSt[t & 15][t >> 4] = w0f[t];
    }
    if (tid < 64) bS[tid] = b0f[tid];
    __syncthreads();

    int pixg = blockIdx.x * 4 + (tid >> 6);       // global pixel id
    int c = tid & 63;
    const float* xin = x + (size_t)(pixg / HWPROD) * 16 * HWPROD + (pixg % HWPROD);
    float acc = bS[c];
#pragma unroll
    for (int cin = 0; cin < 16; cin++)
        acc += wSt[cin][c] * xin[(size_t)cin * HWPROD];
    x1L[(size_t)pixg * 64 + c] = fmaxf(acc, 0.f);
}

// ---------------------------------------------------------------------------
// main fused kernel: one block = 16-pixel row segment.
//  phase0: stage x1 halo tile (3x18x64) + compute WeightNet gz[16pix][9k][16o]
//  loop over 4 c-chunks:
//    phase1: A[pix][c][o] = sum_k patch[c][k]*gz[o][k]   (chunk in LDS)
//    phase2: facc[j] += sum_{c,o} lwT[c*16+o][j]*A[...]  (K=1024 projection)
//  store relu(facc + lbf)
// ---------------------------------------------------------------------------
__global__ __launch_bounds__(256) void pconv_main_k(const float* __restrict__ gxyz,
                                                    const float* __restrict__ x1L,
                                                    const float* __restrict__ lwT,
                                                    const float* __restrict__ lbf,
                                                    const float* __restrict__ wnP,
                                                    float* __restrict__ out)
{
    // paddings: xt col stride 80 (pix-groups land on banks {0,16}: 2-way, free)
    //           Ac row stride 324 (%32==4 -> b128 reads spread, <=2-way)
    //           Ac c stride 20 (16B-aligned, write pattern <=2-way)
    __shared__ float xt[3][18][80];
    __shared__ float gzL[16][144];
    __shared__ float Ac[16][324];
    __shared__ float wnS[248];

    const int tid = threadIdx.x;
    const int bid = blockIdx.x;
    const int b   = bid / (HH * 12);
    const int rem = bid % (HH * 12);
    const int h   = rem / 12;
    const int wc0 = (rem % 12) * 16;

    if (tid < 248) wnS[tid] = wnP[tid];

    // raw local coords for the WeightNet threads (coalesced over pixels)
    float xyz0 = 0.f, xyz1 = 0.f, xyz2 = 0.f;
    const int gpix = tid & 15, gk = tid >> 4;
    if (tid < 144) {
        size_t base = ((size_t)(b * 3) * 9 + gk) * HWPROD + (size_t)h * WW + wc0 + gpix;
        xyz0 = gxyz[base];
        xyz1 = gxyz[base + (size_t)9 * HWPROD];
        xyz2 = gxyz[base + (size_t)18 * HWPROD];
    }

    // stage x1 halo tile: rows h-1..h+1, cols wc0-1..wc0+16, 64 channels; zero OOB
    for (int q = tid; q < 864; q += 256) {
        int c4   = q & 15;
        int colr = q >> 4;
        int col  = colr % 18;
        int r    = colr / 18;
        int hr = h + r - 1;
        int wc = wc0 + col - 1;
        float4 v = make_float4(0.f, 0.f, 0.f, 0.f);
        if (hr >= 0 && hr < HH && wc >= 0 && wc < WW) {
            v = *(const float4*)(x1L + (((size_t)b * HH + hr) * WW + wc) * 64 + c4 * 4);
        }
        *(float4*)&xt[r][col][c4 * 4] = v;
    }
    __syncthreads();

    // WeightNet 3->8->8->16 (BN+ReLU fused), one thread per (pixel, tap)
    if (tid < 144) {
        float h0[8], h1[8];
#pragma unroll
        for (int o = 0; o < 8; o++) {
            float a = wnS[24 + o] + wnS[o * 3 + 0] * xyz0 + wnS[o * 3 + 1] * xyz1 + wnS[o * 3 + 2] * xyz2;
            h0[o] = fmaxf(a, 0.f);
        }
#pragma unroll
        for (int o = 0; o < 8; o++) {
            float a = wnS[96 + o];
#pragma unroll
            for (int c = 0; c < 8; c++) a += wnS[32 + o * 8 + c] * h0[c];
            h1[o] = fmaxf(a, 0.f);
        }
#pragma unroll
        for (int o = 0; o < 16; o++) {
            float a = wnS[232 + o];
#pragma unroll
            for (int c = 0; c < 8; c++) a += wnS[104 + o * 8 + c] * h1[c];
            gzL[gpix][gk * 16 + o] = fmaxf(a, 0.f);
        }
    }
    __syncthreads();

    float facc[4] = {0.f, 0.f, 0.f, 0.f};
    const int p1pix = tid >> 4, p1ci = tid & 15;   // phase-1 roles
    const int jg = tid >> 4, pixq = tid & 15;      // phase-2 roles (j-major for
                                                   // coalesced final stores)
    const float* lwcol = lwT + jg * 4;

    for (int cc = 0; cc < 64; cc += 16) {
        // ---- phase 1: A-chunk ----
        {
            const int c = cc + p1ci;
            float acc[16];
#pragma unroll
            for (int o = 0; o < 16; o++) acc[o] = 0.f;
#pragma unroll
            for (int ky = 0; ky < 3; ky++) {
#pragma unroll
                for (int kx = 0; kx < 3; kx++) {
                    float pk = xt[ky][p1pix + kx][c];
                    const float* gp = &gzL[p1pix][(ky * 3 + kx) * 16];
#pragma unroll
                    for (int o = 0; o < 16; o++) acc[o] += pk * gp[o];
                }
            }
            float* ap = &Ac[p1pix][p1ci * 20];
#pragma unroll
            for (int o = 0; o < 16; o++) ap[o] = acc[o];
        }
        __syncthreads();
        // ---- phase 2: K=256 slice of the 1024->64 projection ----
        {
#pragma unroll 2
            for (int c16 = 0; c16 < 16; c16++) {
                const float* arow = &Ac[pixq][c16 * 20];
                const int kbase = (cc + c16) * 16;
#pragma unroll
                for (int o4 = 0; o4 < 4; o4++) {
                    float4 a = *(const float4*)(arow + o4 * 4);
                    const float* wp = lwcol + (size_t)(kbase + o4 * 4) * 64;
                    float4 wv0 = *(const float4*)(wp);
                    float4 wv1 = *(const float4*)(wp + 64);
                    float4 wv2 = *(const float4*)(wp + 128);
                    float4 wv3 = *(const float4*)(wp + 192);
                    facc[0] += a.x * wv0.x + a.y * wv1.x + a.z * wv2.x + a.w * wv3.x;
                    facc[1] += a.x * wv0.y + a.y * wv1.y + a.z * wv2.y + a.w * wv3.y;
                    facc[2] += a.x * wv0.z + a.y * wv1.z + a.z * wv2.z + a.w * wv3.z;
                    facc[3] += a.x * wv0.w + a.y * wv1.w + a.z * wv2.w + a.w * wv3.w;
                }
            }
        }
        __syncthreads();
    }

    // epilogue: bias + relu, coalesced 64B-segment stores
    size_t ob = ((size_t)b * 64 + jg * 4) * HWPROD + (size_t)h * WW + wc0 + pixq;
#pragma unroll
    for (int i = 0; i < 4; i++) {
        out[ob + (size_t)i * HWPROD] = fmaxf(facc[i] + lbf[jg * 4 + i], 0.f);
    }
}

// ---------------------------------------------------------------------------
extern "C" void kernel_launch(void* const* d_in, const int* in_sizes, int n_in,
                              void* d_out, int out_size, void* d_ws, size_t ws_size,
                              hipStream_t stream) {
    const float* x    = (const float*)d_in[0];
    // d_in[1] = group_mask: unused by the reference
    const float* gxyz = (const float*)d_in[2];

    float* ws  = (float*)d_ws;
    float* x1L = ws;                    // 9,437,184 floats: x1 in [B,H,W,64]
    float* lwT = ws + 9437184;          // 65,536 floats
    float* lbf = lwT + 65536;           // 64
    float* w0f = lbf + 64;              // 1024
    float* b0f = w0f + 1024;            // 64
    float* wnP = b0f + 64;              // 248

    prep_k<<<262, 256, 0, stream>>>(
        (const float*)d_in[3],  (const float*)d_in[4],  (const float*)d_in[5],
        (const float*)d_in[6],  (const float*)d_in[7],  (const float*)d_in[8],
        (const float*)d_in[9],  (const float*)d_in[10], (const float*)d_in[11],
        (const float*)d_in[12], (const float*)d_in[13], (const float*)d_in[14],
        (const float*)d_in[15], (const float*)d_in[16], (const float*)d_in[17],
        (const float*)d_in[18], (const float*)d_in[19], (const float*)d_in[20],
        (const float*)d_in[21], (const float*)d_in[22], (const float*)d_in[23],
        (const float*)d_in[24], (const float*)d_in[25], (const float*)d_in[26],
        (const float*)d_in[27], (const float*)d_in[28], (const float*)d_in[29],
        (const float*)d_in[30], (const float*)d_in[31], (const float*)d_in[32],
        lwT, lbf, w0f, b0f, wnP);

    conv0_k<<<36864, 256, 0, stream>>>(x, w0f, b0f, x1L);

    pconv_main_k<<<4 * HH * 12, 256, 0, stream>>>(gxyz, x1L, lwT, lbf, wnP,
                                                  (float*)d_out);
}

// Round 2
// 348.116 us; speedup vs baseline: 3.7520x; 3.7520x over previous
//
#include <hip/hip_runtime.h>
#include <hip/hip_bf16.h>

#define HH 192
#define WW 192
#define HWPROD (192*192)
#define EPSBN 1e-5f

typedef _Float16 f16x8 __attribute__((ext_vector_type(8)));
typedef float f32x4 __attribute__((ext_vector_type(4)));

union F16Pack { _Float16 h[8]; f16x8 v; };

// ---------------------------------------------------------------------------
// prep: fold BN into conv weights/biases; build MFMA-fragment-major f16 hi/lo
// copies of the final projection weight:
//   whF/wlF[((jg*32+kb)*64 + lane)*8 + j] = lw[n][k]*bnscale(n) split hi/lo,
//   n = jg*16 + (lane&15), k = kb*32 + ((lane>>4)&3)*8 + j
// ---------------------------------------------------------------------------
__global__ void prep_k(const float* __restrict__ w0, const float* __restrict__ b0,
                       const float* __restrict__ g0, const float* __restrict__ beta0,
                       const float* __restrict__ m0, const float* __restrict__ v0,
                       const float* __restrict__ wnw0, const float* __restrict__ wnb0,
                       const float* __restrict__ wng0, const float* __restrict__ wnbe0,
                       const float* __restrict__ wnm0, const float* __restrict__ wnv0,
                       const float* __restrict__ wnw1, const float* __restrict__ wnb1,
                       const float* __restrict__ wng1, const float* __restrict__ wnbe1,
                       const float* __restrict__ wnm1, const float* __restrict__ wnv1,
                       const float* __restrict__ wnw2, const float* __restrict__ wnb2,
                       const float* __restrict__ wng2, const float* __restrict__ wnbe2,
                       const float* __restrict__ wnm2, const float* __restrict__ wnv2,
                       const float* __restrict__ lw, const float* __restrict__ lb,
                       const float* __restrict__ lg, const float* __restrict__ lbeta,
                       const float* __restrict__ lm, const float* __restrict__ lv,
                       _Float16* __restrict__ whF, _Float16* __restrict__ wlF,
                       float* __restrict__ lbf,
                       float* __restrict__ w0f, float* __restrict__ b0f,
                       float* __restrict__ wnP)
{
    int idx = blockIdx.x * 256 + threadIdx.x;
    if (idx < 65536) {
        int j    = idx & 7;
        int lane = (idx >> 3) & 63;
        int kb   = (idx >> 9) & 31;
        int jg   = idx >> 14;
        int k = kb * 32 + ((lane >> 4) & 3) * 8 + j;
        int n = jg * 16 + (lane & 15);
        float s = lg[n] * rsqrtf(lv[n] + EPSBN);
        float w = lw[n * 1024 + k] * s;
        _Float16 hp = (_Float16)w;
        whF[idx] = hp;
        wlF[idx] = (_Float16)(w - (float)hp);
    } else if (idx < 65600) {
        int j = idx - 65536;
        float s = lg[j] * rsqrtf(lv[j] + EPSBN);
        lbf[j] = (lb[j] - lm[j]) * s + lbeta[j];
    } else if (idx < 66624) {
        int t = idx - 65600;
        int o = t >> 4;
        float s = g0[o] * rsqrtf(v0[o] + EPSBN);
        w0f[t] = w0[t] * s;
    } else if (idx < 66688) {
        int o = idx - 66624;
        float s = g0[o] * rsqrtf(v0[o] + EPSBN);
        b0f[o] = (b0[o] - m0[o]) * s + beta0[o];
    } else if (idx < 66936) {
        int t = idx - 66688;
        // wnP layout: [0,24) w0n  [24,32) b0n  [32,96) w1n  [96,104) b1n
        //             [104,232) w2n  [232,248) b2n   (all BN-fused)
        if (t < 24)       { int o = t / 3;           float s = wng0[o] * rsqrtf(wnv0[o] + EPSBN); wnP[t] = wnw0[t] * s; }
        else if (t < 32)  { int o = t - 24;          float s = wng0[o] * rsqrtf(wnv0[o] + EPSBN); wnP[t] = (wnb0[o] - wnm0[o]) * s + wnbe0[o]; }
        else if (t < 96)  { int t2 = t - 32;  int o = t2 >> 3; float s = wng1[o] * rsqrtf(wnv1[o] + EPSBN); wnP[t] = wnw1[t2] * s; }
        else if (t < 104) { int o = t - 96;          float s = wng1[o] * rsqrtf(wnv1[o] + EPSBN); wnP[t] = (wnb1[o] - wnm1[o]) * s + wnbe1[o]; }
        else if (t < 232) { int t2 = t - 104; int o = t2 >> 3; float s = wng2[o] * rsqrtf(wnv2[o] + EPSBN); wnP[t] = wnw2[t2] * s; }
        else              { int o = t - 232;         float s = wng2[o] * rsqrtf(wnv2[o] + EPSBN); wnP[t] = (wnb2[o] - wnm2[o]) * s + wnbe2[o]; }
    }
}

// ---------------------------------------------------------------------------
// conv0: x[B,16,H,W] -> x1 = relu(bn(conv1x1)) stored pixel-major [B,H,W,64]
// ---------------------------------------------------------------------------
__global__ __launch_bounds__(256) void conv0_k(const float* __restrict__ x,
                                               const float* __restrict__ w0f,
                                               const float* __restrict__ b0f,
                                               float* __restrict__ x1L)
{
    __shared__ float wSt[16][64];
    __shared__ float bS[64];
    int tid = threadIdx.x;
    for (int t = tid; t < 1024; t += 256) {
        wSt[t & 15][t >> 4] = w0f[t];
    }
    if (tid < 64) bS[tid] = b0f[tid];
    __syncthreads();

    int pixg = blockIdx.x * 4 + (tid >> 6);
    int c = tid & 63;
    const float* xin = x + (size_t)(pixg / HWPROD) * 16 * HWPROD + (pixg % HWPROD);
    float acc = bS[c];
#pragma unroll
    for (int cin = 0; cin < 16; cin++)
        acc += wSt[cin][c] * xin[(size_t)cin * HWPROD];
    x1L[(size_t)pixg * 64 + c] = fmaxf(acc, 0.f);
}

// ---------------------------------------------------------------------------
// main fused kernel: one block = 16-pixel row segment, 256 threads = 4 waves.
//  phase0: stage x1 halo tile (3x18x64 fp32) + WeightNet gz[16pix][9k][16o]
//  loop cc = 0..3 over 16-channel chunks of x1 (K-chunk of 256):
//    phase1 (fp32 VALU): A[pix][k=c*16+o] = sum_tap patch*gz, split to f16
//            hi/lo and written to LDS in MFMA A-fragment order
//    phase2 (MFMA): wave jg accumulates C[16pix][16j] over the chunk's 8
//            K=32 steps; 3 mfma_f32_16x16x32_f16 per step (hi/lo split)
//  epilogue: transpose C through LDS, bias+relu, coalesced stores
// ---------------------------------------------------------------------------
__global__ __launch_bounds__(256) void pconv_main_k(const float* __restrict__ gxyz,
                                                    const float* __restrict__ x1L,
                                                    const _Float16* __restrict__ whF,
                                                    const _Float16* __restrict__ wlF,
                                                    const float* __restrict__ lbf,
                                                    const float* __restrict__ wnP,
                                                    float* __restrict__ out)
{
    __shared__ float xt[3][18][80];      // halo tile, 2-way max aliasing
    __shared__ float gzL[16][144];       // WeightNet outputs per pixel
    __shared__ float wnS[248];
    __shared__ _Float16 AhF[8 * 520];    // A-chunk hi, fragment-major,
    __shared__ _Float16 AlF[8 * 520];    //   kb-stride 520 halves = 1040 B (pad)
    __shared__ float Cb[64 * 17];        // epilogue transpose buffer

    const int tid = threadIdx.x;
    const int bid = blockIdx.x;
    const int b   = bid / (HH * 12);
    const int rem = bid % (HH * 12);
    const int h   = rem / 12;
    const int wc0 = (rem % 12) * 16;

    if (tid < 248) wnS[tid] = wnP[tid];

    float xyz0 = 0.f, xyz1 = 0.f, xyz2 = 0.f;
    const int gpix = tid & 15, gk = tid >> 4;
    if (tid < 144) {
        size_t base = ((size_t)(b * 3) * 9 + gk) * HWPROD + (size_t)h * WW + wc0 + gpix;
        xyz0 = gxyz[base];
        xyz1 = gxyz[base + (size_t)9 * HWPROD];
        xyz2 = gxyz[base + (size_t)18 * HWPROD];
    }

    // stage x1 halo tile: rows h-1..h+1, cols wc0-1..wc0+16, 64 ch; zero OOB
    for (int q = tid; q < 864; q += 256) {
        int c4   = q & 15;
        int colr = q >> 4;
        int col  = colr % 18;
        int r    = colr / 18;
        int hr = h + r - 1;
        int wc = wc0 + col - 1;
        float4 v = make_float4(0.f, 0.f, 0.f, 0.f);
        if (hr >= 0 && hr < HH && wc >= 0 && wc < WW) {
            v = *(const float4*)(x1L + (((size_t)b * HH + hr) * WW + wc) * 64 + c4 * 4);
        }
        *(float4*)&xt[r][col][c4 * 4] = v;
    }
    __syncthreads();

    // WeightNet 3->8->8->16 (BN+ReLU fused), one thread per (pixel, tap)
    if (tid < 144) {
        float h0[8], h1[8];
#pragma unroll
        for (int o = 0; o < 8; o++) {
            float a = wnS[24 + o] + wnS[o * 3 + 0] * xyz0 + wnS[o * 3 + 1] * xyz1 + wnS[o * 3 + 2] * xyz2;
            h0[o] = fmaxf(a, 0.f);
        }
#pragma unroll
        for (int o = 0; o < 8; o++) {
            float a = wnS[96 + o];
#pragma unroll
            for (int c = 0; c < 8; c++) a += wnS[32 + o * 8 + c] * h0[c];
            h1[o] = fmaxf(a, 0.f);
        }
#pragma unroll
        for (int o = 0; o < 16; o++) {
            float a = wnS[232 + o];
#pragma unroll
            for (int c = 0; c < 8; c++) a += wnS[104 + o * 8 + c] * h1[c];
            gzL[gpix][gk * 16 + o] = fmaxf(a, 0.f);
        }
    }
    __syncthreads();

    const int pix  = tid >> 4, ci = tid & 15;   // phase-1 roles
    const int jg   = tid >> 6, lane = tid & 63; // phase-2 roles (wave = N-tile)
    const f16x8* whF8 = (const f16x8*)whF;
    const f16x8* wlF8 = (const f16x8*)wlF;

    f32x4 facc = {0.f, 0.f, 0.f, 0.f};

    for (int cc = 0; cc < 4; cc++) {
        // ---- phase 1: A-chunk (fp32), write f16 hi/lo fragments ----
        {
            const int c = cc * 16 + ci;
            float acc[16];
#pragma unroll
            for (int o = 0; o < 16; o++) acc[o] = 0.f;
#pragma unroll
            for (int ky = 0; ky < 3; ky++) {
#pragma unroll
                for (int kx = 0; kx < 3; kx++) {
                    float pk = xt[ky][pix + kx][c];
                    const float4* gp = (const float4*)&gzL[pix][(ky * 3 + kx) * 16];
                    float4 g0v = gp[0], g1v = gp[1], g2v = gp[2], g3v = gp[3];
                    acc[0]  += pk * g0v.x; acc[1]  += pk * g0v.y; acc[2]  += pk * g0v.z; acc[3]  += pk * g0v.w;
                    acc[4]  += pk * g1v.x; acc[5]  += pk * g1v.y; acc[6]  += pk * g1v.z; acc[7]  += pk * g1v.w;
                    acc[8]  += pk * g2v.x; acc[9]  += pk * g2v.y; acc[10] += pk * g2v.z; acc[11] += pk * g2v.w;
                    acc[12] += pk * g3v.x; acc[13] += pk * g3v.y; acc[14] += pk * g3v.z; acc[15] += pk * g3v.w;
                }
            }
            F16Pack vh0, vh1, vl0, vl1;
#pragma unroll
            for (int o = 0; o < 8; o++) {
                float a0 = acc[o], a1 = acc[o + 8];
                _Float16 h0 = (_Float16)a0, h1 = (_Float16)a1;
                vh0.h[o] = h0; vl0.h[o] = (_Float16)(a0 - (float)h0);
                vh1.h[o] = h1; vl1.h[o] = (_Float16)(a1 - (float)h1);
            }
            // klocal = ci*16 + o  ->  kb = ci>>1, lane = pix + 32*(ci&1) (+16)
            const int kb = ci >> 1;
            const int laneA = pix + 32 * (ci & 1);
            *(f16x8*)&AhF[kb * 520 + laneA * 8]        = vh0.v;
            *(f16x8*)&AhF[kb * 520 + (laneA + 16) * 8] = vh1.v;
            *(f16x8*)&AlF[kb * 520 + laneA * 8]        = vl0.v;
            *(f16x8*)&AlF[kb * 520 + (laneA + 16) * 8] = vl1.v;
        }
        __syncthreads();
        // ---- phase 2: 8 MFMA K-steps over the chunk ----
        {
#pragma unroll
            for (int kb = 0; kb < 8; kb++) {
                const int kg = cc * 8 + kb;
                f16x8 ah = *(const f16x8*)&AhF[kb * 520 + lane * 8];
                f16x8 al = *(const f16x8*)&AlF[kb * 520 + lane * 8];
                f16x8 wh = whF8[((jg * 32 + kg) << 6) + lane];
                f16x8 wl = wlF8[((jg * 32 + kg) << 6) + lane];
                facc = __builtin_amdgcn_mfma_f32_16x16x32_f16(ah, wh, facc, 0, 0, 0);
                facc = __builtin_amdgcn_mfma_f32_16x16x32_f16(al, wh, facc, 0, 0, 0);
                facc = __builtin_amdgcn_mfma_f32_16x16x32_f16(ah, wl, facc, 0, 0, 0);
            }
        }
        __syncthreads();
    }

    // epilogue: C/D layout col=lane&15 (=j within tile), row=(lane>>4)*4+reg (=pix)
    {
        const int n  = jg * 16 + (lane & 15);
        const int m0 = (lane >> 4) * 4;
#pragma unroll
        for (int r = 0; r < 4; r++) Cb[n * 17 + m0 + r] = facc[r];
    }
    __syncthreads();
    {
        const int pixq = tid & 15, jq = tid >> 4;
        size_t ob = ((size_t)b * 64 + jq * 4) * HWPROD + (size_t)h * WW + wc0 + pixq;
#pragma unroll
        for (int i = 0; i < 4; i++) {
            out[ob + (size_t)i * HWPROD] = fmaxf(Cb[(jq * 4 + i) * 17 + pixq] + lbf[jq * 4 + i], 0.f);
        }
    }
}

// ---------------------------------------------------------------------------
extern "C" void kernel_launch(void* const* d_in, const int* in_sizes, int n_in,
                              void* d_out, int out_size, void* d_ws, size_t ws_size,
                              hipStream_t stream) {
    const float* x    = (const float*)d_in[0];
    // d_in[1] = group_mask: unused by the reference
    const float* gxyz = (const float*)d_in[2];

    float* ws  = (float*)d_ws;
    float* x1L = ws;                               // 9,437,184 floats
    _Float16* whF = (_Float16*)(ws + 9437184);     // 65,536 halves
    _Float16* wlF = whF + 65536;                   // 65,536 halves
    float* lbf = (float*)(wlF + 65536);            // 64
    float* w0f = lbf + 64;                         // 1024
    float* b0f = w0f + 1024;                       // 64
    float* wnP = b0f + 64;                         // 248

    prep_k<<<262, 256, 0, stream>>>(
        (const float*)d_in[3],  (const float*)d_in[4],  (const float*)d_in[5],
        (const float*)d_in[6],  (const float*)d_in[7],  (const float*)d_in[8],
        (const float*)d_in[9],  (const float*)d_in[10], (const float*)d_in[11],
        (const float*)d_in[12], (const float*)d_in[13], (const float*)d_in[14],
        (const float*)d_in[15], (const float*)d_in[16], (const float*)d_in[17],
        (const float*)d_in[18], (const float*)d_in[19], (const float*)d_in[20],
        (const float*)d_in[21], (const float*)d_in[22], (const float*)d_in[23],
        (const float*)d_in[24], (const float*)d_in[25], (const float*)d_in[26],
        (const float*)d_in[27], (const float*)d_in[28], (const float*)d_in[29],
        (const float*)d_in[30], (const float*)d_in[31], (const float*)d_in[32],
        whF, wlF, lbf, w0f, b0f, wnP);

    conv0_k<<<36864, 256, 0, stream>>>(x, w0f, b0f, x1L);

    pconv_main_k<<<4 * HH * 12, 256, 0, stream>>>(gxyz, x1L, whF, wlF, lbf, wnP,
                                                  (float*)d_out);
}

// Round 3
// 275.891 us; speedup vs baseline: 4.7342x; 1.2618x over previous
//
#include <hip/hip_runtime.h>
#include <hip/hip_bf16.h>

#define HH 192
#define WW 192
#define HWPROD (192*192)
#define EPSBN 1e-5f

typedef _Float16 f16x8 __attribute__((ext_vector_type(8)));
typedef _Float16 f16x4 __attribute__((ext_vector_type(4)));
typedef float f32x4 __attribute__((ext_vector_type(4)));

// ---------------------------------------------------------------------------
// prep: fold BN into conv weights/biases; build MFMA-fragment-major f16 hi/lo
// copies of the final projection weight:
//   whF/wlF[((jg*32+kb)*64 + lane)*8 + j] = lw[n][k]*bnscale(n) split hi/lo,
//   n = jg*16 + (lane&15), k = kb*32 + ((lane>>4)&3)*8 + j
// ---------------------------------------------------------------------------
__global__ void prep_k(const float* __restrict__ w0, const float* __restrict__ b0,
                       const float* __restrict__ g0, const float* __restrict__ beta0,
                       const float* __restrict__ m0, const float* __restrict__ v0,
                       const float* __restrict__ wnw0, const float* __restrict__ wnb0,
                       const float* __restrict__ wng0, const float* __restrict__ wnbe0,
                       const float* __restrict__ wnm0, const float* __restrict__ wnv0,
                       const float* __restrict__ wnw1, const float* __restrict__ wnb1,
                       const float* __restrict__ wng1, const float* __restrict__ wnbe1,
                       const float* __restrict__ wnm1, const float* __restrict__ wnv1,
                       const float* __restrict__ wnw2, const float* __restrict__ wnb2,
                       const float* __restrict__ wng2, const float* __restrict__ wnbe2,
                       const float* __restrict__ wnm2, const float* __restrict__ wnv2,
                       const float* __restrict__ lw, const float* __restrict__ lb,
                       const float* __restrict__ lg, const float* __restrict__ lbeta,
                       const float* __restrict__ lm, const float* __restrict__ lv,
                       _Float16* __restrict__ whF, _Float16* __restrict__ wlF,
                       float* __restrict__ lbf,
                       float* __restrict__ w0f, float* __restrict__ b0f,
                       float* __restrict__ wnP)
{
    int idx = blockIdx.x * 256 + threadIdx.x;
    if (idx < 65536) {
        int j    = idx & 7;
        int lane = (idx >> 3) & 63;
        int kb   = (idx >> 9) & 31;
        int jg   = idx >> 14;
        int k = kb * 32 + ((lane >> 4) & 3) * 8 + j;
        int n = jg * 16 + (lane & 15);
        float s = lg[n] * rsqrtf(lv[n] + EPSBN);
        float w = lw[n * 1024 + k] * s;
        _Float16 hp = (_Float16)w;
        whF[idx] = hp;
        wlF[idx] = (_Float16)(w - (float)hp);
    } else if (idx < 65600) {
        int j = idx - 65536;
        float s = lg[j] * rsqrtf(lv[j] + EPSBN);
        lbf[j] = (lb[j] - lm[j]) * s + lbeta[j];
    } else if (idx < 66624) {
        int t = idx - 65600;
        int o = t >> 4;
        float s = g0[o] * rsqrtf(v0[o] + EPSBN);
        w0f[t] = w0[t] * s;
    } else if (idx < 66688) {
        int o = idx - 66624;
        float s = g0[o] * rsqrtf(v0[o] + EPSBN);
        b0f[o] = (b0[o] - m0[o]) * s + beta0[o];
    } else if (idx < 66936) {
        int t = idx - 66688;
        // wnP layout: [0,24) w0n  [24,32) b0n  [32,96) w1n  [96,104) b1n
        //             [104,232) w2n  [232,248) b2n   (all BN-fused)
        if (t < 24)       { int o = t / 3;           float s = wng0[o] * rsqrtf(wnv0[o] + EPSBN); wnP[t] = wnw0[t] * s; }
        else if (t < 32)  { int o = t - 24;          float s = wng0[o] * rsqrtf(wnv0[o] + EPSBN); wnP[t] = (wnb0[o] - wnm0[o]) * s + wnbe0[o]; }
        else if (t < 96)  { int t2 = t - 32;  int o = t2 >> 3; float s = wng1[o] * rsqrtf(wnv1[o] + EPSBN); wnP[t] = wnw1[t2] * s; }
        else if (t < 104) { int o = t - 96;          float s = wng1[o] * rsqrtf(wnv1[o] + EPSBN); wnP[t] = (wnb1[o] - wnm1[o]) * s + wnbe1[o]; }
        else if (t < 232) { int t2 = t - 104; int o = t2 >> 3; float s = wng2[o] * rsqrtf(wnv2[o] + EPSBN); wnP[t] = wnw2[t2] * s; }
        else              { int o = t - 232;         float s = wng2[o] * rsqrtf(wnv2[o] + EPSBN); wnP[t] = (wnb2[o] - wnm2[o]) * s + wnbe2[o]; }
    }
}

// ---------------------------------------------------------------------------
// conv0: x[B,16,H,W] -> x1 = relu(bn(conv1x1)) stored pixel-major [B,H,W,64]
// lane = pixel: 16 coalesced input loads to regs; weights are wave-uniform ->
// scalar (s_load) path; 1024 FMAs/thread; float4 stores.
// ---------------------------------------------------------------------------
__global__ __launch_bounds__(256) void conv0_k(const float* __restrict__ x,
                                               const float* __restrict__ w0f,
                                               const float* __restrict__ b0f,
                                               float* __restrict__ x1L)
{
    const int pix = blockIdx.x * 256 + threadIdx.x;   // grid covers exactly B*H*W
    const int b = pix / HWPROD;
    const int p = pix - b * HWPROD;

    float xv[16];
#pragma unroll
    for (int cin = 0; cin < 16; cin++)
        xv[cin] = x[((size_t)b * 16 + cin) * HWPROD + p];

    float* outp = x1L + (size_t)pix * 64;
#pragma unroll
    for (int co = 0; co < 64; co += 4) {
        f32x4 a = { b0f[co], b0f[co + 1], b0f[co + 2], b0f[co + 3] };
#pragma unroll
        for (int cin = 0; cin < 16; cin++) {
            float xc = xv[cin];
            a.x += w0f[(co + 0) * 16 + cin] * xc;
            a.y += w0f[(co + 1) * 16 + cin] * xc;
            a.z += w0f[(co + 2) * 16 + cin] * xc;
            a.w += w0f[(co + 3) * 16 + cin] * xc;
        }
        a.x = fmaxf(a.x, 0.f); a.y = fmaxf(a.y, 0.f);
        a.z = fmaxf(a.z, 0.f); a.w = fmaxf(a.w, 0.f);
        *(f32x4*)(outp + co) = a;
    }
}

// ---------------------------------------------------------------------------
// main fused kernel: one block = 16-pixel row segment, 256 threads = 4 waves.
//  phase0: stage x1 halo (3x18x64 fp32) + WeightNet gz[16pix][9k][16o] (fp32)
//  thread role (phase1): (pix, cq, oq) computes 4c x 4o; its gz-quad (9 taps)
//  lives in registers across all chunks; xt read as float4 (no re-reads).
//  A written as f16 (single) in MFMA A-fragment order.
//  phase2: wave jg: per kb, 1 LDS b128 A-read + 2 global weight reads +
//  2 mfma_f32_16x16x32_f16 (A-single x W-hi/lo).
//  epilogue: C transposed through LDS (aliased over xt) -> coalesced stores.
//  LDS total 35,808 B -> 4 blocks/CU.
// ---------------------------------------------------------------------------
__global__ __launch_bounds__(256) void pconv_main_k(const float* __restrict__ gxyz,
                                                    const float* __restrict__ x1L,
                                                    const _Float16* __restrict__ whF,
                                                    const _Float16* __restrict__ wlF,
                                                    const float* __restrict__ lbf,
                                                    const float* __restrict__ wnP,
                                                    float* __restrict__ out)
{
    __shared__ __align__(16) char smem[35808];
    float (*xt)[18][80] = reinterpret_cast<float(*)[18][80]>(smem);        // 17280 B
    float (*gzL)[144]   = reinterpret_cast<float(*)[144]>(smem + 17280);   //  9216 B
    _Float16* AhF       = reinterpret_cast<_Float16*>(smem + 26496);       //  8320 B (8 kb x 520 halves)
    float* wnS          = reinterpret_cast<float*>(smem + 34816);          //   992 B
    float* Cb           = reinterpret_cast<float*>(smem);                  // aliases xt (used post-loop)

    const int tid = threadIdx.x;
    const int bid = blockIdx.x;
    const int b   = bid / (HH * 12);
    const int rem = bid % (HH * 12);
    const int h   = rem / 12;
    const int wc0 = (rem % 12) * 16;

    if (tid < 248) wnS[tid] = wnP[tid];

    float xyz0 = 0.f, xyz1 = 0.f, xyz2 = 0.f;
    const int gpix = tid & 15, gk = tid >> 4;
    if (tid < 144) {
        size_t base = ((size_t)(b * 3) * 9 + gk) * HWPROD + (size_t)h * WW + wc0 + gpix;
        xyz0 = gxyz[base];
        xyz1 = gxyz[base + (size_t)9 * HWPROD];
        xyz2 = gxyz[base + (size_t)18 * HWPROD];
    }

    // stage x1 halo tile: rows h-1..h+1, cols wc0-1..wc0+16, 64 ch; zero OOB
    for (int q = tid; q < 864; q += 256) {
        int c4   = q & 15;
        int colr = q >> 4;
        int col  = colr % 18;
        int r    = colr / 18;
        int hr = h + r - 1;
        int wc = wc0 + col - 1;
        f32x4 v = {0.f, 0.f, 0.f, 0.f};
        if (hr >= 0 && hr < HH && wc >= 0 && wc < WW) {
            v = *(const f32x4*)(x1L + (((size_t)b * HH + hr) * WW + wc) * 64 + c4 * 4);
        }
        *(f32x4*)&xt[r][col][c4 * 4] = v;
    }
    __syncthreads();

    // WeightNet 3->8->8->16 (BN+ReLU fused), one thread per (pixel, tap)
    if (tid < 144) {
        float h0[8], h1[8];
#pragma unroll
        for (int o = 0; o < 8; o++) {
            float a = wnS[24 + o] + wnS[o * 3 + 0] * xyz0 + wnS[o * 3 + 1] * xyz1 + wnS[o * 3 + 2] * xyz2;
            h0[o] = fmaxf(a, 0.f);
        }
#pragma unroll
        for (int o = 0; o < 8; o++) {
            float a = wnS[96 + o];
#pragma unroll
            for (int c = 0; c < 8; c++) a += wnS[32 + o * 8 + c] * h0[c];
            h1[o] = fmaxf(a, 0.f);
        }
#pragma unroll
        for (int o = 0; o < 16; o++) {
            float a = wnS[232 + o];
#pragma unroll
            for (int c = 0; c < 8; c++) a += wnS[104 + o * 8 + c] * h1[c];
            gzL[gpix][gk * 16 + o] = fmaxf(a, 0.f);
        }
    }
    __syncthreads();

    // phase-1 roles: 4 c's x 4 o's per thread
    const int pix = tid >> 4;
    const int cq  = tid & 3;
    const int oq  = (tid >> 2) & 3;
    // phase-2 roles
    const int jg = tid >> 6, lane = tid & 63;
    const f16x8* whF8 = (const f16x8*)whF;
    const f16x8* wlF8 = (const f16x8*)wlF;

    // gz quad (4 o's, 9 taps) in registers for the whole K loop
    f32x4 gq[9];
#pragma unroll
    for (int t = 0; t < 9; t++)
        gq[t] = *(const f32x4*)&gzL[pix][t * 16 + oq * 4];

    f32x4 facc = {0.f, 0.f, 0.f, 0.f};

    for (int cc = 0; cc < 4; cc++) {
        // ---- phase 1: A-chunk (fp32 acc), write f16 fragments ----
        {
            const int c0 = cc * 16 + cq * 4;
            f32x4 a0 = {0,0,0,0}, a1 = {0,0,0,0}, a2 = {0,0,0,0}, a3 = {0,0,0,0};
#pragma unroll
            for (int ky = 0; ky < 3; ky++) {
#pragma unroll
                for (int kx = 0; kx < 3; kx++) {
                    f32x4 xq = *(const f32x4*)&xt[ky][pix + kx][c0];
                    f32x4 g  = gq[ky * 3 + kx];
                    a0 += xq.x * g;
                    a1 += xq.y * g;
                    a2 += xq.z * g;
                    a3 += xq.w * g;
                }
            }
            // write 4 x b64: k_local = c_local*16 + o; fragment mapping:
            // kb=c_local>>1, laneF=pix+16*((c_local&1)*2+(oq>>1)), j=(oq&1)*4+jo
            const int wbase = (oq & 1) * 4;
            const int lsel  = 16 * ((oq >> 1));
#pragma unroll
            for (int i = 0; i < 4; i++) {
                const int cl = cq * 4 + i;
                const int kb = cl >> 1;
                const int laneF = pix + lsel + 16 * ((cl & 1) * 2);
                f32x4 av = (i == 0) ? a0 : (i == 1) ? a1 : (i == 2) ? a2 : a3;
                f16x4 hv = __builtin_convertvector(av, f16x4);
                *(f16x4*)&AhF[kb * 520 + laneF * 8 + wbase] = hv;
            }
        }
        __syncthreads();
        // ---- phase 2: 8 MFMA K-steps over the chunk ----
        {
#pragma unroll
            for (int kb = 0; kb < 8; kb++) {
                const int kg = cc * 8 + kb;
                f16x8 ah = *(const f16x8*)&AhF[kb * 520 + lane * 8];
                f16x8 wh = whF8[((jg * 32 + kg) << 6) + lane];
                f16x8 wl = wlF8[((jg * 32 + kg) << 6) + lane];
                facc = __builtin_amdgcn_mfma_f32_16x16x32_f16(ah, wh, facc, 0, 0, 0);
                facc = __builtin_amdgcn_mfma_f32_16x16x32_f16(ah, wl, facc, 0, 0, 0);
            }
        }
        __syncthreads();
    }

    // epilogue: C/D layout col=lane&15 (=j), row=(lane>>4)*4+reg (=pix)
    {
        const int n  = jg * 16 + (lane & 15);
        const int m0 = (lane >> 4) * 4;
#pragma unroll
        for (int r = 0; r < 4; r++) Cb[n * 17 + m0 + r] = facc[r];
    }
    __syncthreads();
    {
        const int pixq = tid & 15, jq = tid >> 4;
        size_t ob = ((size_t)b * 64 + jq * 4) * HWPROD + (size_t)h * WW + wc0 + pixq;
#pragma unroll
        for (int i = 0; i < 4; i++) {
            out[ob + (size_t)i * HWPROD] = fmaxf(Cb[(jq * 4 + i) * 17 + pixq] + lbf[jq * 4 + i], 0.f);
        }
    }
}

// ---------------------------------------------------------------------------
extern "C" void kernel_launch(void* const* d_in, const int* in_sizes, int n_in,
                              void* d_out, int out_size, void* d_ws, size_t ws_size,
                              hipStream_t stream) {
    const float* x    = (const float*)d_in[0];
    // d_in[1] = group_mask: unused by the reference
    const float* gxyz = (const float*)d_in[2];

    float* ws  = (float*)d_ws;
    float* x1L = ws;                               // 9,437,184 floats
    _Float16* whF = (_Float16*)(ws + 9437184);     // 65,536 halves
    _Float16* wlF = whF + 65536;                   // 65,536 halves
    float* lbf = (float*)(wlF + 65536);            // 64
    float* w0f = lbf + 64;                         // 1024
    float* b0f = w0f + 1024;                       // 64
    float* wnP = b0f + 64;                         // 248

    prep_k<<<262, 256, 0, stream>>>(
        (const float*)d_in[3],  (const float*)d_in[4],  (const float*)d_in[5],
        (const float*)d_in[6],  (const float*)d_in[7],  (const float*)d_in[8],
        (const float*)d_in[9],  (const float*)d_in[10], (const float*)d_in[11],
        (const float*)d_in[12], (const float*)d_in[13], (const float*)d_in[14],
        (const float*)d_in[15], (const float*)d_in[16], (const float*)d_in[17],
        (const float*)d_in[18], (const float*)d_in[19], (const float*)d_in[20],
        (const float*)d_in[21], (const float*)d_in[22], (const float*)d_in[23],
        (const float*)d_in[24], (const float*)d_in[25], (const float*)d_in[26],
        (const float*)d_in[27], (const float*)d_in[28], (const float*)d_in[29],
        (const float*)d_in[30], (const float*)d_in[31], (const float*)d_in[32],
        whF, wlF, lbf, w0f, b0f, wnP);

    conv0_k<<<576, 256, 0, stream>>>(x, w0f, b0f, x1L);

    pconv_main_k<<<4 * HH * 12, 256, 0, stream>>>(gxyz, x1L, whF, wlF, lbf, wnP,
                                                  (float*)d_out);
}

// Round 4
// 264.902 us; speedup vs baseline: 4.9306x; 1.0415x over previous
//
#include <hip/hip_runtime.h>
#include <hip/hip_bf16.h>

#define HH 192
#define WW 192
#define HWPROD (192*192)
#define EPSBN 1e-5f

typedef _Float16 f16x8 __attribute__((ext_vector_type(8)));
typedef _Float16 f16x4 __attribute__((ext_vector_type(4)));
typedef float f32x4 __attribute__((ext_vector_type(4)));

// ---------------------------------------------------------------------------
// prep: fold BN into conv weights/biases; build MFMA-fragment-major f16 hi/lo
// copies of the final projection weight:
//   whF/wlF[((jg*32+kb)*64 + lane)*8 + j] = lw[n][k]*bnscale(n) split hi/lo,
//   n = jg*16 + (lane&15), k = kb*32 + ((lane>>4)&3)*8 + j
// ---------------------------------------------------------------------------
__global__ void prep_k(const float* __restrict__ w0, const float* __restrict__ b0,
                       const float* __restrict__ g0, const float* __restrict__ beta0,
                       const float* __restrict__ m0, const float* __restrict__ v0,
                       const float* __restrict__ wnw0, const float* __restrict__ wnb0,
                       const float* __restrict__ wng0, const float* __restrict__ wnbe0,
                       const float* __restrict__ wnm0, const float* __restrict__ wnv0,
                       const float* __restrict__ wnw1, const float* __restrict__ wnb1,
                       const float* __restrict__ wng1, const float* __restrict__ wnbe1,
                       const float* __restrict__ wnm1, const float* __restrict__ wnv1,
                       const float* __restrict__ wnw2, const float* __restrict__ wnb2,
                       const float* __restrict__ wng2, const float* __restrict__ wnbe2,
                       const float* __restrict__ wnm2, const float* __restrict__ wnv2,
                       const float* __restrict__ lw, const float* __restrict__ lb,
                       const float* __restrict__ lg, const float* __restrict__ lbeta,
                       const float* __restrict__ lm, const float* __restrict__ lv,
                       _Float16* __restrict__ whF, _Float16* __restrict__ wlF,
                       float* __restrict__ lbf,
                       float* __restrict__ w0f, float* __restrict__ b0f,
                       float* __restrict__ wnP)
{
    int idx = blockIdx.x * 256 + threadIdx.x;
    if (idx < 65536) {
        int j    = idx & 7;
        int lane = (idx >> 3) & 63;
        int kb   = (idx >> 9) & 31;
        int jg   = idx >> 14;
        int k = kb * 32 + ((lane >> 4) & 3) * 8 + j;
        int n = jg * 16 + (lane & 15);
        float s = lg[n] * rsqrtf(lv[n] + EPSBN);
        float w = lw[n * 1024 + k] * s;
        _Float16 hp = (_Float16)w;
        whF[idx] = hp;
        wlF[idx] = (_Float16)(w - (float)hp);
    } else if (idx < 65600) {
        int j = idx - 65536;
        float s = lg[j] * rsqrtf(lv[j] + EPSBN);
        lbf[j] = (lb[j] - lm[j]) * s + lbeta[j];
    } else if (idx < 66624) {
        int t = idx - 65600;
        int o = t >> 4;
        float s = g0[o] * rsqrtf(v0[o] + EPSBN);
        w0f[t] = w0[t] * s;
    } else if (idx < 66688) {
        int o = idx - 66624;
        float s = g0[o] * rsqrtf(v0[o] + EPSBN);
        b0f[o] = (b0[o] - m0[o]) * s + beta0[o];
    } else if (idx < 66936) {
        int t = idx - 66688;
        // wnP layout: [0,24) w0n  [24,32) b0n  [32,96) w1n  [96,104) b1n
        //             [104,232) w2n  [232,248) b2n   (all BN-fused)
        if (t < 24)       { int o = t / 3;           float s = wng0[o] * rsqrtf(wnv0[o] + EPSBN); wnP[t] = wnw0[t] * s; }
        else if (t < 32)  { int o = t - 24;          float s = wng0[o] * rsqrtf(wnv0[o] + EPSBN); wnP[t] = (wnb0[o] - wnm0[o]) * s + wnbe0[o]; }
        else if (t < 96)  { int t2 = t - 32;  int o = t2 >> 3; float s = wng1[o] * rsqrtf(wnv1[o] + EPSBN); wnP[t] = wnw1[t2] * s; }
        else if (t < 104) { int o = t - 96;          float s = wng1[o] * rsqrtf(wnv1[o] + EPSBN); wnP[t] = (wnb1[o] - wnm1[o]) * s + wnbe1[o]; }
        else if (t < 232) { int t2 = t - 104; int o = t2 >> 3; float s = wng2[o] * rsqrtf(wnv2[o] + EPSBN); wnP[t] = wnw2[t2] * s; }
        else              { int o = t - 232;         float s = wng2[o] * rsqrtf(wnv2[o] + EPSBN); wnP[t] = (wnb2[o] - wnm2[o]) * s + wnbe2[o]; }
    }
}

// ---------------------------------------------------------------------------
// conv0: x[B,16,H,W] -> x1 = relu(bn(conv1x1)) stored pixel-major f16 [B,H,W,64]
// lane = pixel: 16 coalesced input loads to regs; weights via uniform scalar
// loads; 1024 FMAs/thread; f16x4 stores (halved HBM write traffic).
// ---------------------------------------------------------------------------
__global__ __launch_bounds__(256) void conv0_k(const float* __restrict__ x,
                                               const float* __restrict__ w0f,
                                               const float* __restrict__ b0f,
                                               _Float16* __restrict__ x1L)
{
    const int pix = blockIdx.x * 256 + threadIdx.x;   // grid covers exactly B*H*W
    const int b = pix / HWPROD;
    const int p = pix - b * HWPROD;

    float xv[16];
#pragma unroll
    for (int cin = 0; cin < 16; cin++)
        xv[cin] = x[((size_t)b * 16 + cin) * HWPROD + p];

    _Float16* outp = x1L + (size_t)pix * 64;
#pragma unroll
    for (int co = 0; co < 64; co += 4) {
        f32x4 a = { b0f[co], b0f[co + 1], b0f[co + 2], b0f[co + 3] };
#pragma unroll
        for (int cin = 0; cin < 16; cin++) {
            float xc = xv[cin];
            a.x += w0f[(co + 0) * 16 + cin] * xc;
            a.y += w0f[(co + 1) * 16 + cin] * xc;
            a.z += w0f[(co + 2) * 16 + cin] * xc;
            a.w += w0f[(co + 3) * 16 + cin] * xc;
        }
        a.x = fmaxf(a.x, 0.f); a.y = fmaxf(a.y, 0.f);
        a.z = fmaxf(a.z, 0.f); a.w = fmaxf(a.w, 0.f);
        *(f16x4*)(outp + co) = __builtin_convertvector(a, f16x4);
    }
}

// ---------------------------------------------------------------------------
// main fused kernel: one block = 16-pixel row segment, 256 threads = 4 waves.
//  phase0: stage f16 x1 halo (3x18x64) + WeightNet gz (f16) -- ONE barrier
//  K-loop with double-buffered A (one barrier per chunk):
//    phase1: (pix,cq,oq) computes 4c x 4o in fp32 from f16 xt / reg-resident
//            gz quad; writes f16 MFMA A-fragments to buf[(cc+1)&1]
//    phase2: wave jg: per kb, 1 b128 A-read + 2 global 16B weight reads +
//            2 x mfma_f32_16x16x32_f16 (A x W-hi/lo)
//  epilogue: C transposed through LDS (aliased over xt) -> coalesced stores
//  LDS ~31.1 KB -> 5 blocks/CU.
// ---------------------------------------------------------------------------
__global__ __launch_bounds__(256) void pconv_main_k(const float* __restrict__ gxyz,
                                                    const _Float16* __restrict__ x1L,
                                                    const _Float16* __restrict__ whF,
                                                    const _Float16* __restrict__ wlF,
                                                    const float* __restrict__ lbf,
                                                    const float* __restrict__ wnP,
                                                    float* __restrict__ out)
{
    __shared__ __align__(16) char smem[31136];
    _Float16 (*xt)[18][80] = reinterpret_cast<_Float16(*)[18][80]>(smem);   //  8640 B
    _Float16 (*gzF)[152]   = reinterpret_cast<_Float16(*)[152]>(smem + 8640); // 4864 B
    _Float16* A0           = reinterpret_cast<_Float16*>(smem + 13504);     //  8320 B
    _Float16* A1           = reinterpret_cast<_Float16*>(smem + 21824);     //  8320 B
    float* wnS             = reinterpret_cast<float*>(smem + 30144);        //   992 B
    float* Cb              = reinterpret_cast<float*>(smem);                // aliases xt

    const int tid = threadIdx.x;
    const int bid = blockIdx.x;
    const int b   = bid / (HH * 12);
    const int rem = bid % (HH * 12);
    const int h   = rem / 12;
    const int wc0 = (rem % 12) * 16;

    if (tid < 248) wnS[tid] = wnP[tid];

    float xyz0 = 0.f, xyz1 = 0.f, xyz2 = 0.f;
    const int gpix = tid & 15, gk = tid >> 4;
    if (tid < 144) {
        size_t base = ((size_t)(b * 3) * 9 + gk) * HWPROD + (size_t)h * WW + wc0 + gpix;
        xyz0 = gxyz[base];
        xyz1 = gxyz[base + (size_t)9 * HWPROD];
        xyz2 = gxyz[base + (size_t)18 * HWPROD];
    }

    // stage f16 x1 halo: rows h-1..h+1, cols wc0-1..wc0+16, 64 ch; zero OOB
    for (int q = tid; q < 432; q += 256) {
        int c8   = q & 7;
        int colr = q >> 3;
        int col  = colr % 18;
        int r    = colr / 18;
        int hr = h + r - 1;
        int wc = wc0 + col - 1;
        f16x8 v = {};
        if (hr >= 0 && hr < HH && wc >= 0 && wc < WW) {
            v = *(const f16x8*)(x1L + (((size_t)b * HH + hr) * WW + wc) * 64 + c8 * 8);
        }
        *(f16x8*)&xt[r][col][c8 * 8] = v;
    }

    // WeightNet 3->8->8->16 (BN+ReLU fused), one thread per (pixel, tap)
    // (only reads wnS + regs; writes gzF -- covered by the same barrier as xt)
    if (tid < 144) {
        float h0[8], h1[8];
#pragma unroll
        for (int o = 0; o < 8; o++) {
            float a = wnS[24 + o] + wnS[o * 3 + 0] * xyz0 + wnS[o * 3 + 1] * xyz1 + wnS[o * 3 + 2] * xyz2;
            h0[o] = fmaxf(a, 0.f);
        }
#pragma unroll
        for (int o = 0; o < 8; o++) {
            float a = wnS[96 + o];
#pragma unroll
            for (int c = 0; c < 8; c++) a += wnS[32 + o * 8 + c] * h0[c];
            h1[o] = fmaxf(a, 0.f);
        }
        float g[16];
#pragma unroll
        for (int o = 0; o < 16; o++) {
            float a = wnS[232 + o];
#pragma unroll
            for (int c = 0; c < 8; c++) a += wnS[104 + o * 8 + c] * h1[c];
            g[o] = fmaxf(a, 0.f);
        }
        f16x8 lo, hi;
#pragma unroll
        for (int o = 0; o < 8; o++) { lo[o] = (_Float16)g[o]; hi[o] = (_Float16)g[o + 8]; }
        *(f16x8*)&gzF[gpix][gk * 16]     = lo;
        *(f16x8*)&gzF[gpix][gk * 16 + 8] = hi;
    }
    __syncthreads();   // S1: xt + gzF visible

    // phase-1 roles: 4 c's x 4 o's per thread
    const int pix = tid >> 4;
    const int cq  = tid & 3;
    const int oq  = (tid >> 2) & 3;
    // phase-2 roles
    const int jg = tid >> 6, lane = tid & 63;
    const f16x8* whF8 = (const f16x8*)whF;
    const f16x8* wlF8 = (const f16x8*)wlF;

    // gz quad (4 o's, 9 taps) in registers for the whole K loop
    f32x4 gq[9];
#pragma unroll
    for (int t = 0; t < 9; t++)
        gq[t] = __builtin_convertvector(*(const f16x4*)&gzF[pix][t * 16 + oq * 4], f32x4);

    const int wbase = (oq & 1) * 4;
    const int lsel  = 16 * (oq >> 1);

    // phase-1 body as a lambda over (chunk cc, destination buffer)
    auto phase1 = [&](int cc, _Float16* Abuf) {
        const int c0 = cc * 16 + cq * 4;
        f32x4 a0 = {0,0,0,0}, a1 = {0,0,0,0}, a2 = {0,0,0,0}, a3 = {0,0,0,0};
#pragma unroll
        for (int ky = 0; ky < 3; ky++) {
#pragma unroll
            for (int kx = 0; kx < 3; kx++) {
                f32x4 xq = __builtin_convertvector(*(const f16x4*)&xt[ky][pix + kx][c0], f32x4);
                f32x4 g  = gq[ky * 3 + kx];
                a0 += xq.x * g;
                a1 += xq.y * g;
                a2 += xq.z * g;
                a3 += xq.w * g;
            }
        }
        // k_local = c_local*16 + o; fragment: kb=cl>>1,
        // laneF = pix + 16*(oq>>1) + 32*(cl&1), j = (oq&1)*4 + jo
#pragma unroll
        for (int i = 0; i < 4; i++) {
            const int cl = cq * 4 + i;
            const int kb = cl >> 1;
            const int laneF = pix + lsel + 32 * (cl & 1);
            f32x4 av = (i == 0) ? a0 : (i == 1) ? a1 : (i == 2) ? a2 : a3;
            *(f16x4*)&Abuf[kb * 520 + laneF * 8 + wbase] = __builtin_convertvector(av, f16x4);
        }
    };

    f32x4 facc = {0.f, 0.f, 0.f, 0.f};

    phase1(0, A0);
    __syncthreads();   // S2: A(0) ready

#pragma unroll
    for (int cc = 0; cc < 4; cc++) {
        const _Float16* Acur = (cc & 1) ? A1 : A0;
        // ---- phase 2: 8 MFMA K-steps over chunk cc ----
#pragma unroll
        for (int kb = 0; kb < 8; kb++) {
            const int kg = cc * 8 + kb;
            f16x8 ah = *(const f16x8*)&Acur[kb * 520 + lane * 8];
            f16x8 wh = whF8[((jg * 32 + kg) << 6) + lane];
            f16x8 wl = wlF8[((jg * 32 + kg) << 6) + lane];
            facc = __builtin_amdgcn_mfma_f32_16x16x32_f16(ah, wh, facc, 0, 0, 0);
            facc = __builtin_amdgcn_mfma_f32_16x16x32_f16(ah, wl, facc, 0, 0, 0);
        }
        // ---- phase 1 of next chunk into the other buffer ----
        if (cc < 3) {
            phase1(cc + 1, (cc & 1) ? A0 : A1);
            __syncthreads();   // S3..S5: A(cc+1) ready (also fences A(cc) reuse)
        }
    }

    // epilogue: C/D layout col=lane&15 (=j), row=(lane>>4)*4+reg (=pix)
    // Cb aliases xt: safe -- last xt reads were phase1(3), before S5.
    {
        const int n  = jg * 16 + (lane & 15);
        const int m0 = (lane >> 4) * 4;
#pragma unroll
        for (int r = 0; r < 4; r++) Cb[n * 17 + m0 + r] = facc[r];
    }
    __syncthreads();   // S6
    {
        const int pixq = tid & 15, jq = tid >> 4;
        size_t ob = ((size_t)b * 64 + jq * 4) * HWPROD + (size_t)h * WW + wc0 + pixq;
#pragma unroll
        for (int i = 0; i < 4; i++) {
            out[ob + (size_t)i * HWPROD] = fmaxf(Cb[(jq * 4 + i) * 17 + pixq] + lbf[jq * 4 + i], 0.f);
        }
    }
}

// ---------------------------------------------------------------------------
extern "C" void kernel_launch(void* const* d_in, const int* in_sizes, int n_in,
                              void* d_out, int out_size, void* d_ws, size_t ws_size,
                              hipStream_t stream) {
    const float* x    = (const float*)d_in[0];
    // d_in[1] = group_mask: unused by the reference
    const float* gxyz = (const float*)d_in[2];

    char* ws = (char*)d_ws;
    _Float16* x1L = (_Float16*)ws;                        // 9,437,184 halves (18.9 MB)
    _Float16* whF = x1L + 9437184;                        // 65,536 halves
    _Float16* wlF = whF + 65536;                          // 65,536 halves
    float* lbf = (float*)(wlF + 65536);                   // 64
    float* w0f = lbf + 64;                                // 1024
    float* b0f = w0f + 1024;                              // 64
    float* wnP = b0f + 64;                                // 248

    prep_k<<<262, 256, 0, stream>>>(
        (const float*)d_in[3],  (const float*)d_in[4],  (const float*)d_in[5],
        (const float*)d_in[6],  (const float*)d_in[7],  (const float*)d_in[8],
        (const float*)d_in[9],  (const float*)d_in[10], (const float*)d_in[11],
        (const float*)d_in[12], (const float*)d_in[13], (const float*)d_in[14],
        (const float*)d_in[15], (const float*)d_in[16], (const float*)d_in[17],
        (const float*)d_in[18], (const float*)d_in[19], (const float*)d_in[20],
        (const float*)d_in[21], (const float*)d_in[22], (const float*)d_in[23],
        (const float*)d_in[24], (const float*)d_in[25], (const float*)d_in[26],
        (const float*)d_in[27], (const float*)d_in[28], (const float*)d_in[29],
        (const float*)d_in[30], (const float*)d_in[31], (const float*)d_in[32],
        whF, wlF, lbf, w0f, b0f, wnP);

    conv0_k<<<576, 256, 0, stream>>>(x, w0f, b0f, x1L);

    pconv_main_k<<<4 * HH * 12, 256, 0, stream>>>(gxyz, x1L, whF, wlF, lbf, wnP,
                                                  (float*)d_out);
}